// Round 3
// baseline (9931.042 us; speedup 1.0000x reference)
//
#include <hip/hip_runtime.h>

// MultiRegionRNN: T=500 sequential steps, per-step fused GEMM
//   x = 0.9*x + 0.1*(R_ext @ W_ext^T + b), r = tanh(x)
// R_ext[b, 0:512]=r_m1, [512:1024]=r_pmd, [1024:1026]=out_prev, [1026:1036]=u_prev, [1036:1040]=0
// W_ext row i<512  : [W_rec_M1 | W_pmd_m1 | W_fb | 0...]
// W_ext row i>=512 : [W_m1_pmd | W_rec_PMd | 0 0 | W_in_pmd | 0...]

#define NT 500
#define NB 128
#define NU 512
#define NR 1024
#define KE 1040
#define LSTR 1044   // LDS row stride (1044%32=20 -> 8 rows hit 8 distinct bank quads)

__global__ __launch_bounds__(256) void prep_kernel(
    const float* __restrict__ Wrm1, const float* __restrict__ Wpm,
    const float* __restrict__ Wmp,  const float* __restrict__ WrP,
    const float* __restrict__ Win,  const float* __restrict__ Wfb,
    const float* __restrict__ bM1,  const float* __restrict__ bP,
    float* __restrict__ Wext, float* __restrict__ bbig)
{
    int i = blockIdx.x, tid = threadIdx.x;
    float* row = Wext + (size_t)i * KE;
    if (i < NU) {
        for (int c = tid; c < NU; c += 256) row[c]      = Wrm1[i * NU + c];
        for (int c = tid; c < NU; c += 256) row[NU + c] = Wpm[i * NU + c];
    } else {
        int j = i - NU;
        for (int c = tid; c < NU; c += 256) row[c]      = Wmp[j * NU + c];
        for (int c = tid; c < NU; c += 256) row[NU + c] = WrP[j * NU + c];
    }
    if (tid < 16) {  // cols 1024..1039
        float v = 0.f;
        if (i < NU) {
            if (tid < 2) v = Wfb[i * 2 + tid];
        } else {
            if (tid >= 2 && tid < 12) v = Win[(i - NU) * 10 + (tid - 2)];
        }
        row[1024 + tid] = v;
    }
    if (tid == 0) bbig[i] = (i < NU) ? bM1[i] : bP[i - NU];
}

__global__ __launch_bounds__(256) void step_kernel(
    const float* __restrict__ stim, const float* __restrict__ Wext,
    const float* __restrict__ bbig, const float* __restrict__ Wout,
    float* __restrict__ outs, float* __restrict__ rm1, float* __restrict__ rpmd,
    float* __restrict__ xst, int t)
{
    __shared__ float Rext[8][LSTR];
    __shared__ float partial[16][17];
    const int tid = threadIdx.x;
    const int rt = blockIdx.x & 15;   // row tile (0..15): XCD = blockIdx%8 = rt%8 -> weight rows L2-local
    const int bt = blockIdx.x >> 4;   // batch tile (0..15)
    const int b0 = bt * 8;

    // ---- stage R_ext rates part (k 0..1023) ----
    if (t == 1) {
        #pragma unroll
        for (int b = 0; b < 8; ++b)
            ((float4*)&Rext[b][0])[tid] = make_float4(0.f, 0.f, 0.f, 0.f);
    } else {
        const float* rm1s = rm1  + (size_t)(t - 1) * NB * NU;
        const float* rps  = rpmd + (size_t)(t - 1) * NB * NU;
        int k = tid * 4;
        #pragma unroll
        for (int b = 0; b < 8; ++b) {
            const float* src = (k < NU) ? (rm1s + (size_t)(b0 + b) * NU + k)
                                        : (rps  + (size_t)(b0 + b) * NU + (k - NU));
            ((float4*)&Rext[b][0])[tid] = *(const float4*)src;
        }
    }
    // stim tail (u_prev = stim[t-1]) and zero pad
    if (tid < 80) {
        int b = tid / 10, j = tid % 10;
        Rext[b][1026 + j] = stim[(size_t)(t - 1) * NB * 10 + (size_t)(b0 + b) * 10 + j];
    } else if (tid < 80 + 64) {
        int q = tid - 80;
        Rext[q / 8][1036 + (q % 8)] = 0.f;
    }
    __syncthreads();

    // ---- out_prev[b,d] = sum_k Wout[d,k] * r_m1_prev[b,k]  (zeros at t==1 automatically) ----
    {
        int p = tid >> 4, sub = tid & 15;
        int b = p >> 1, d = p & 1;
        const float* wo = Wout + d * NU + sub * 32;
        const float* rr = &Rext[b][sub * 32];
        float s = 0.f;
        #pragma unroll
        for (int k = 0; k < 32; ++k) s = fmaf(wo[k], rr[k], s);
        partial[p][sub] = s;
    }
    __syncthreads();
    if (tid < 16) {
        float o = 0.f;
        #pragma unroll
        for (int j = 0; j < 16; ++j) o += partial[tid][j];
        int b = tid >> 1, d = tid & 1;
        Rext[b][1024 + d] = o;
        if (rt == 0) outs[(size_t)(t - 1) * NB * 2 + (size_t)(b0 + b) * 2 + d] = o;
    }
    __syncthreads();

    // ---- main GEMM: 64 rows x 8 batches, K=1040; thread = 2 rows x 1 batch ----
    const int rp_ = tid >> 3, bi = tid & 7;
    const int r0 = rt * 64 + rp_ * 2, r1 = r0 + 1;
    const float4* __restrict__ w0 = (const float4*)(Wext + (size_t)r0 * KE);
    const float4* __restrict__ w1 = (const float4*)(Wext + (size_t)r1 * KE);
    const float4* __restrict__ rv = (const float4*)&Rext[bi][0];
    float a0 = 0.f, a1 = 0.f;
    #pragma unroll 4
    for (int kk = 0; kk < KE / 4; ++kk) {
        float4 x = w0[kk], y = w1[kk], r = rv[kk];
        a0 = fmaf(x.x, r.x, a0); a0 = fmaf(x.y, r.y, a0);
        a0 = fmaf(x.z, r.z, a0); a0 = fmaf(x.w, r.w, a0);
        a1 = fmaf(y.x, r.x, a1); a1 = fmaf(y.y, r.y, a1);
        a1 = fmaf(y.z, r.z, a1); a1 = fmaf(y.w, r.w, a1);
    }

    // ---- leaky integrate + tanh + write state/rates ----
    const int gb = b0 + bi;
    {
        size_t xi = (size_t)gb * NR + r0;
        float xo = (t == 1) ? 0.f : xst[xi];
        float xn = 0.9f * xo + 0.1f * (a0 + bbig[r0]);
        xst[xi] = xn;
        float rr2 = tanhf(xn);
        if (r0 < NU) rm1[(size_t)t * NB * NU + (size_t)gb * NU + r0] = rr2;
        else         rpmd[(size_t)t * NB * NU + (size_t)gb * NU + (r0 - NU)] = rr2;
    }
    {
        size_t xi = (size_t)gb * NR + r1;
        float xo = (t == 1) ? 0.f : xst[xi];
        float xn = 0.9f * xo + 0.1f * (a1 + bbig[r1]);
        xst[xi] = xn;
        float rr2 = tanhf(xn);
        if (r1 < NU) rm1[(size_t)t * NB * NU + (size_t)gb * NU + r1] = rr2;
        else         rpmd[(size_t)t * NB * NU + (size_t)gb * NU + (r1 - NU)] = rr2;
    }

    // ---- t==0 outputs are zeros (tanh(0)=0); write them once in the t==1 kernel ----
    if (t == 1 && rt == 0) {
        for (int i = tid; i < 8 * NU; i += 256) {
            int b = i >> 9, k = i & 511;
            rm1 [(size_t)(b0 + b) * NU + k] = 0.f;
            rpmd[(size_t)(b0 + b) * NU + k] = 0.f;
        }
    }
}

__global__ __launch_bounds__(256) void final_out_kernel(
    const float* __restrict__ Wout, const float* __restrict__ rm1,
    float* __restrict__ outs)
{
    int tid = threadIdx.x;
    int b = tid >> 1, d = tid & 1;
    const float* r = rm1 + (size_t)(NT - 1) * NB * NU + (size_t)b * NU;
    const float* w = Wout + d * NU;
    float s = 0.f;
    for (int k = 0; k < NU; ++k) s = fmaf(w[k], r[k], s);
    outs[(size_t)(NT - 1) * NB * 2 + b * 2 + d] = s;
}

extern "C" void kernel_launch(void* const* d_in, const int* in_sizes, int n_in,
                              void* d_out, int out_size, void* d_ws, size_t ws_size,
                              hipStream_t stream) {
    const float* stim = (const float*)d_in[0];
    const float* Wrm1 = (const float*)d_in[1];
    const float* bM1  = (const float*)d_in[2];
    const float* WrP  = (const float*)d_in[3];
    const float* bP   = (const float*)d_in[4];
    const float* Wpm  = (const float*)d_in[5];
    const float* Wmp  = (const float*)d_in[6];
    const float* Win  = (const float*)d_in[7];
    const float* Wout = (const float*)d_in[8];
    const float* Wfb  = (const float*)d_in[9];

    float* outs = (float*)d_out;                    // [500,128,2]
    float* rm1  = outs + (size_t)NT * NB * 2;       // [500,128,512]
    float* rpmd = rm1 + (size_t)NT * NB * NU;       // [500,128,512]

    float* ws   = (float*)d_ws;
    float* Wext = ws;                                // 1024*1040
    float* bbig = Wext + (size_t)NR * KE;            // 1024
    float* xst  = bbig + NR;                         // 128*1024 persistent x state

    prep_kernel<<<NR, 256, 0, stream>>>(Wrm1, Wpm, Wmp, WrP, Win, Wfb, bM1, bP, Wext, bbig);
    for (int t = 1; t < NT; ++t)
        step_kernel<<<256, 256, 0, stream>>>(stim, Wext, bbig, Wout, outs, rm1, rpmd, xst, t);
    final_out_kernel<<<1, 256, 0, stream>>>(Wout, rm1, outs);
}

// Round 5
// 6774.607 us; speedup vs baseline: 1.4659x; 1.4659x over previous
//
#include <hip/hip_runtime.h>

// MultiRegionRNN: 500 sequential steps, per-step fused GEMM
//   x = 0.9*x + 0.1*(R_ext @ W_ext^T + b), r = tanh(x)
// R_ext[b, 0:512]=r_m1, [512:1024]=r_pmd, [1024:1026]=out_prev, [1026:1036]=u_prev, [1036:1040]=0
// W_ext row i<512  : [W_rec_M1 | W_pmd_m1 | W_fb | 0...]
// W_ext row i>=512 : [W_m1_pmd | W_rec_PMd | 0 0 | W_in_pmd | 0...]
//
// Step kernel: 256 blocks x 512 thr. Block = 64 rows x 8 batches.
// Wave = 8 rows x 8 batches, lanes = k-slices; rates reused across rows in VGPRs.
// 64->1 reduce: merge tree with TRUE xor exchanges only:
//   bit0 quad_perm(0xB1), bit1 quad_perm(0x4E), bit3 ROW_ROR:8 (l^8 within 16-row),
//   bit2 shfl_xor(4), bit4 shfl_xor(16), bit5 shfl_xor(32).
// Stage order (0,1,3,2,4,5) -> cell idx = 8*b2+4*b3+2*b1+b0 + 32*b5+16*b4:
//   rr = (lane&3)|((lane>>1)&4), bb = ((lane>>2)&1)|((lane>>3)&6).

#define NT 500
#define NB 128
#define NU 512
#define NR 1024
#define KE 1040
#define RS 1088   // LDS row stride (floats)

template<int CTRL>
__device__ __forceinline__ float dppsum(float v) {
    int t = __builtin_amdgcn_update_dpp(0, __float_as_int(v), CTRL, 0xF, 0xF, true);
    return v + __int_as_float(t);
}

__global__ __launch_bounds__(256) void prep_kernel(
    const float* __restrict__ Wrm1, const float* __restrict__ Wpm,
    const float* __restrict__ Wmp,  const float* __restrict__ WrP,
    const float* __restrict__ Win,  const float* __restrict__ Wfb,
    const float* __restrict__ bM1,  const float* __restrict__ bP,
    float* __restrict__ Wext, float* __restrict__ bbig)
{
    int i = blockIdx.x, tid = threadIdx.x;
    float* row = Wext + (size_t)i * KE;
    if (i < NU) {
        for (int c = tid; c < NU; c += 256) row[c]      = Wrm1[i * NU + c];
        for (int c = tid; c < NU; c += 256) row[NU + c] = Wpm[i * NU + c];
    } else {
        int j = i - NU;
        for (int c = tid; c < NU; c += 256) row[c]      = Wmp[j * NU + c];
        for (int c = tid; c < NU; c += 256) row[NU + c] = WrP[j * NU + c];
    }
    if (tid < 16) {  // cols 1024..1039
        float v = 0.f;
        if (i < NU) {
            if (tid < 2) v = Wfb[i * 2 + tid];
        } else {
            if (tid >= 2 && tid < 12) v = Win[(i - NU) * 10 + (tid - 2)];
        }
        row[1024 + tid] = v;
    }
    if (tid == 0) bbig[i] = (i < NU) ? bM1[i] : bP[i - NU];
}

__global__ __launch_bounds__(512) void step_kernel(
    const float* __restrict__ stim, const float* __restrict__ Wext,
    const float* __restrict__ bbig, const float* __restrict__ Wout,
    float* __restrict__ outs, float* __restrict__ rm1, float* __restrict__ rpmd,
    float* __restrict__ xst, int t)
{
    __shared__ float Rext[8][RS];
    __shared__ float partial[16][17];
    const int tid  = threadIdx.x;
    const int lane = tid & 63;
    const int w    = tid >> 6;        // wave 0..7
    const int rt = blockIdx.x & 15;   // row tile: XCD = blockIdx%8 = rt%8 -> weights L2-local
    const int bt = blockIdx.x >> 4;   // batch tile
    const int b0 = bt * 8;

    // ---- stage rates (k 0..1023) + zero pad ----
    if (t == 1) {
        float* flat = &Rext[0][0];
        for (int i = tid; i < 8 * RS; i += 512) flat[i] = 0.f;
    } else {
        const float* rm1s = rm1  + (size_t)(t - 1) * NB * NU;
        const float* rps  = rpmd + (size_t)(t - 1) * NB * NU;
        int bb = tid >> 6, j = tid & 63;   // 8 batches x 64 threads
        const float4* s1 = (const float4*)(rm1s + (size_t)(b0 + bb) * NU);
        const float4* s2 = (const float4*)(rps  + (size_t)(b0 + bb) * NU);
        float4* dst = (float4*)&Rext[bb][0];
        dst[j]       = s1[j];
        dst[j + 64]  = s1[j + 64];
        dst[j + 128] = s2[j];
        dst[j + 192] = s2[j + 64];
        if (j < 20) Rext[bb][1036 + j] = 0.f;   // 1036..1055 pad
    }
    __syncthreads();

    // ---- stim tail (u_prev = stim[t-1]) + out_prev partials ----
    if (tid < 80) {
        int b = tid / 10, j = tid % 10;
        Rext[b][1026 + j] = stim[(size_t)(t - 1) * NB * 10 + (size_t)(b0 + b) * 10 + j];
    }
    if (tid < 256) {  // out_prev[b,d] = Wout[d,:] . r_m1_prev[b,:]
        int p = tid >> 4, sub = tid & 15;
        int b = p >> 1, d = p & 1;
        const float* wo = Wout + d * NU + sub * 32;
        const float* rr = &Rext[b][sub * 32];
        float s = 0.f;
        #pragma unroll
        for (int k = 0; k < 32; ++k) s = fmaf(wo[k], rr[k], s);
        partial[p][sub] = s;
    }
    __syncthreads();
    if (tid < 16) {
        float o = 0.f;
        #pragma unroll
        for (int j = 0; j < 16; ++j) o += partial[tid][j];
        int b = tid >> 1, d = tid & 1;
        Rext[b][1024 + d] = o;
        if (rt == 0) outs[(size_t)(t - 1) * NB * 2 + (size_t)(b0 + b) * 2 + d] = o;
    }
    __syncthreads();

    // ---- main GEMM: wave w owns rows rt*64 + w*8 + rr (rr<8), all 8 batches ----
    const int rowbase = rt * 64 + w * 8;
    float acc[64];                      // acc[bb*8+rr], partial over this lane's k-slice
    #pragma unroll
    for (int i = 0; i < 64; ++i) acc[i] = 0.f;

    const int l4 = lane * 4;
    #pragma unroll
    for (int kc = 0; kc < 4; ++kc) {
        float4 r4[8];
        #pragma unroll
        for (int bb = 0; bb < 8; ++bb)
            r4[bb] = *(const float4*)&Rext[bb][kc * 256 + l4];
        #pragma unroll
        for (int rr = 0; rr < 8; ++rr) {
            float4 w4 = *(const float4*)(Wext + (size_t)(rowbase + rr) * KE + kc * 256 + l4);
            #pragma unroll
            for (int bb = 0; bb < 8; ++bb) {
                float a = acc[bb * 8 + rr];
                a = fmaf(w4.x, r4[bb].x, a);
                a = fmaf(w4.y, r4[bb].y, a);
                a = fmaf(w4.z, r4[bb].z, a);
                a = fmaf(w4.w, r4[bb].w, a);
                acc[bb * 8 + rr] = a;
            }
        }
    }
    // K tail 1024..1039: lanes 0..15, one k each (w=0 beyond 1039 in Wext prep)
    {
        const bool act = lane < 16;
        float rr4[8];
        #pragma unroll
        for (int bb = 0; bb < 8; ++bb) rr4[bb] = act ? Rext[bb][1024 + lane] : 0.f;
        #pragma unroll
        for (int rr = 0; rr < 8; ++rr) {
            float wv = act ? Wext[(size_t)(rowbase + rr) * KE + 1024 + lane] : 0.f;
            #pragma unroll
            for (int bb = 0; bb < 8; ++bb)
                acc[bb * 8 + rr] = fmaf(wv, rr4[bb], acc[bb * 8 + rr]);
        }
    }

    // ---- merge-tree reduce (true XOR exchanges only) ----
    #pragma unroll
    for (int i = 0; i < 32; ++i) {                       // bit0: quad_perm xor1
        float ra = dppsum<0xB1>(acc[2 * i]);
        float rb = dppsum<0xB1>(acc[2 * i + 1]);
        acc[i] = (lane & 1) ? rb : ra;
    }
    #pragma unroll
    for (int i = 0; i < 16; ++i) {                       // bit1: quad_perm xor2
        float ra = dppsum<0x4E>(acc[2 * i]);
        float rb = dppsum<0x4E>(acc[2 * i + 1]);
        acc[i] = (lane & 2) ? rb : ra;
    }
    #pragma unroll
    for (int i = 0; i < 8; ++i) {                        // bit3: ROW_ROR:8 == l^8 in 16-row
        float ra = dppsum<0x128>(acc[2 * i]);
        float rb = dppsum<0x128>(acc[2 * i + 1]);
        acc[i] = (lane & 8) ? rb : ra;
    }
    #pragma unroll
    for (int i = 0; i < 4; ++i) {                        // bit2: shfl_xor 4
        float ra = acc[2 * i]     + __shfl_xor(acc[2 * i], 4, 64);
        float rb = acc[2 * i + 1] + __shfl_xor(acc[2 * i + 1], 4, 64);
        acc[i] = (lane & 4) ? rb : ra;
    }
    #pragma unroll
    for (int i = 0; i < 2; ++i) {                        // bit4: shfl_xor 16
        float ra = acc[2 * i]     + __shfl_xor(acc[2 * i], 16, 64);
        float rb = acc[2 * i + 1] + __shfl_xor(acc[2 * i + 1], 16, 64);
        acc[i] = (lane & 16) ? rb : ra;
    }
    {                                                    // bit5: shfl_xor 32
        float ra = acc[0] + __shfl_xor(acc[0], 32, 64);
        float rb = acc[1] + __shfl_xor(acc[1], 32, 64);
        acc[0] = (lane & 32) ? rb : ra;
    }

    // ---- leaky integrate + tanh + write ----
    // cell idx = 32*b5 + 16*b4 + 8*b2 + 4*b3 + 2*b1 + b0 (stage order 0,1,3,2,4,5)
    {
        const int rr = (lane & 3) | ((lane >> 1) & 4);
        const int bb = ((lane >> 2) & 1) | ((lane >> 3) & 6);
        const int row = rowbase + rr;
        const int gb  = b0 + bb;
        size_t xi = (size_t)gb * NR + row;
        float xo = (t == 1) ? 0.f : xst[xi];
        float xn = 0.9f * xo + 0.1f * (acc[0] + bbig[row]);
        xst[xi] = xn;
        float rv = tanhf(xn);
        if (row < NU) rm1[(size_t)t * NB * NU + (size_t)gb * NU + row] = rv;
        else          rpmd[(size_t)t * NB * NU + (size_t)gb * NU + (row - NU)] = rv;
    }

    // ---- t==0 rates are zeros; write them once in the t==1 kernel ----
    if (t == 1 && rt == 0) {
        for (int i = tid; i < 8 * NU; i += 512) {
            int b = i >> 9, k = i & 511;
            rm1 [(size_t)(b0 + b) * NU + k] = 0.f;
            rpmd[(size_t)(b0 + b) * NU + k] = 0.f;
        }
    }
}

__global__ __launch_bounds__(256) void final_out_kernel(
    const float* __restrict__ Wout, const float* __restrict__ rm1,
    float* __restrict__ outs)
{
    int tid = threadIdx.x;
    int b = tid >> 1, d = tid & 1;
    const float* r = rm1 + (size_t)(NT - 1) * NB * NU + (size_t)b * NU;
    const float* wp = Wout + d * NU;
    float s = 0.f;
    for (int k = 0; k < NU; ++k) s = fmaf(wp[k], r[k], s);
    outs[(size_t)(NT - 1) * NB * 2 + b * 2 + d] = s;
}

extern "C" void kernel_launch(void* const* d_in, const int* in_sizes, int n_in,
                              void* d_out, int out_size, void* d_ws, size_t ws_size,
                              hipStream_t stream) {
    const float* stim = (const float*)d_in[0];
    const float* Wrm1 = (const float*)d_in[1];
    const float* bM1  = (const float*)d_in[2];
    const float* WrP  = (const float*)d_in[3];
    const float* bP   = (const float*)d_in[4];
    const float* Wpm  = (const float*)d_in[5];
    const float* Wmp  = (const float*)d_in[6];
    const float* Win  = (const float*)d_in[7];
    const float* Wout = (const float*)d_in[8];
    const float* Wfb  = (const float*)d_in[9];

    float* outs = (float*)d_out;                    // [500,128,2]
    float* rm1  = outs + (size_t)NT * NB * 2;       // [500,128,512]
    float* rpmd = rm1 + (size_t)NT * NB * NU;       // [500,128,512]

    float* ws   = (float*)d_ws;
    float* Wext = ws;                                // 1024*1040
    float* bbig = Wext + (size_t)NR * KE;            // 1024
    float* xst  = bbig + NR;                         // 128*1024 persistent x state

    prep_kernel<<<NR, 256, 0, stream>>>(Wrm1, Wpm, Wmp, WrP, Win, Wfb, bM1, bP, Wext, bbig);
    for (int t = 1; t < NT; ++t)
        step_kernel<<<256, 512, 0, stream>>>(stim, Wext, bbig, Wout, outs, rm1, rpmd, xst, t);
    final_out_kernel<<<1, 256, 0, stream>>>(Wout, rm1, outs);
}